// Round 8
// baseline (260.301 us; speedup 1.0000x reference)
//
#include <hip/hip_runtime.h>

#define B_N 32768
#define D 512
#define DD (D * D)
#define NLEV 10
#define TM 128
#define TN 128
#define BK 32
#define NITER (D / BK)            // 16
#define NHB 128                   // histogram blocks (B_N / 256)
#define MROWS_MAX 34048           // 266*128; >= 32768 + 10*127 pad
#define NRT (MROWS_MAX / TM)      // 266 row tiles
#define NCT (D / TN)              // 4 col tiles
#define NBLK (NRT * NCT)          // 1064 = 8 * 133 (XCD-bijective)
#define CPX (NBLK / 8)            // 133 blocks per XCD chunk

typedef unsigned short u16;
typedef short s16x8 __attribute__((ext_vector_type(8)));
typedef u16 u16x8 __attribute__((ext_vector_type(8)));
typedef float f32x4 __attribute__((ext_vector_type(4)));

__device__ __forceinline__ u16 f2bf(float f) {
  union { float f; unsigned u; } v; v.f = f;
  unsigned r = v.u + 0x7fffu + ((v.u >> 16) & 1u);  // RNE
  return (u16)(r >> 16);
}
__device__ __forceinline__ int clampv(int v) {
  return v < 0 ? 0 : (v > NLEV - 1 ? NLEV - 1 : v);
}

// ---- K1: weff-build (blocks 0..1023) UNION hist+perm-fill (blocks 1024..1151)
__global__ void k1(const float* __restrict__ W, const float* __restrict__ lg,
                   const float* __restrict__ attn, const int* __restrict__ val,
                   u16* __restrict__ weff, u16* __restrict__ hist,
                   int* __restrict__ perm) {
  const int t = threadIdx.x;
  if (blockIdx.x < DD / 256) {
    __shared__ float c[NLEV * NLEV];
    if (t < NLEV) {
      float g[NLEV], a[NLEV], mx = -1e30f;
      #pragma unroll
      for (int l = 0; l < NLEV; ++l) {
        g[l] = 1.0f / (1.0f + expf(-lg[l]));
        a[l] = attn[t * NLEV + l];
        mx = fmaxf(mx, a[l]);
      }
      float s = 0.f;
      #pragma unroll
      for (int l = 0; l < NLEV; ++l) { a[l] = expf(a[l] - mx); s += a[l]; }
      float inv = 1.0f / s;
      #pragma unroll
      for (int l = 0; l < NLEV; ++l) {
        float cc = 0.3f * a[l] * inv * g[l];
        if (l == t) cc += 0.7f * g[t];
        c[t * NLEV + l] = cc;
      }
    }
    __syncthreads();
    const int idx = blockIdx.x * 256 + t;
    float w[NLEV];
    #pragma unroll
    for (int l = 0; l < NLEV; ++l) w[l] = W[l * DD + idx];
    #pragma unroll
    for (int v = 0; v < NLEV; ++v) {
      float s = 0.f;
      #pragma unroll
      for (int l = 0; l < NLEV; ++l) s += c[v * NLEV + l] * w[l];
      weff[v * DD + idx] = f2bf(s);
    }
  } else {
    __shared__ int lc[NLEV];
    const int b = blockIdx.x - DD / 256;   // 0..127
    if (t < NLEV) lc[t] = 0;
    __syncthreads();
    const int gid = b * 256 + t;
    atomicAdd(&lc[clampv(val[gid])], 1);
    perm[gid] = -1;
    if (b < (MROWS_MAX - B_N) / 256) perm[B_N + b * 256 + t] = -1;
    __syncthreads();
    if (t < NLEV) hist[b * NLEV + t] = (u16)lc[t];
  }
}

// ---- K2: deterministic counting-sort scatter (prefix over hist table) ------
__global__ void k2(const int* __restrict__ val, const u16* __restrict__ hist,
                   int* __restrict__ perm, int* __restrict__ starts) {
  __shared__ int h[NHB * NLEV];
  __shared__ int st[NLEV + 1];
  __shared__ int cnt[NLEV];
  __shared__ int lc[NLEV];
  const int t = threadIdx.x, b = blockIdx.x;
  for (int i = t; i < NHB * NLEV; i += 256) h[i] = hist[i];
  if (t < NLEV) lc[t] = 0;
  __syncthreads();
  if (t < NLEV) {
    int run = 0;
    for (int bb = 0; bb < NHB; ++bb) {
      int x = h[bb * NLEV + t];
      h[bb * NLEV + t] = run;
      run += x;
    }
    cnt[t] = run;
  }
  __syncthreads();
  if (t == 0) {
    int s = 0;
    for (int v = 0; v < NLEV; ++v) {
      st[v] = s;
      s += (cnt[v] + TM - 1) & ~(TM - 1);
    }
    st[NLEV] = s;
  }
  __syncthreads();
  const int gid = b * 256 + t;
  const int v = clampv(val[gid]);
  const int pos = atomicAdd(&lc[v], 1);
  perm[st[v] + h[b * NLEV + v] + pos] = gid;
  if (b == 0 && t <= NLEV) starts[t] = st[t];
}

// ---- K3: grouped GEMM, 128x128 tile, XCD-swizzled, counted-vmcnt dbuf ------
// R2's verified 128x128/4-wave structure (32KB LDS -> up to 5 blocks/CU,
// 4+ independent barrier groups per CU) with two fixes:
//  * XCD-bijective swizzle (1064 = 8*133): each XCD owns a contiguous
//    rt-major chunk, so the 4 col-blocks of a row-tile share one private L2
//    (kills R2's +61MB x re-fetch).
//  * R4's counted pre-barrier wait, corrected count: at the wait point the
//    per-wave FIFO is [x(i+1) drained-by-use, B(i+1)x2, x(i+2)x4], so
//    vmcnt(4) drains exactly B(i+1) and keeps all 4 x-loads in flight.
// No loop unroll pragma, depth-1 x FIFO (R6 proved deeper => scratch spill).
__global__ __launch_bounds__(256, 4) void k3(
    const float* __restrict__ x, const u16* __restrict__ weff,
    const int* __restrict__ perm, const int* __restrict__ starts,
    const float* __restrict__ bias, float* __restrict__ out) {
  __shared__ u16 As[2][TM * BK];   // 2 x 8 KB
  __shared__ u16 Bs[2][TN * BK];   // 2 x 8 KB

  const int L = blockIdx.x;
  const int xcd = L & 7, jj = L >> 3;
  const int phys = xcd * CPX + jj;        // contiguous rt-major chunk per XCD
  const int ct = phys & 3, rt = phys >> 2;

  const int Mpad = starts[NLEV];
  if (rt * TM >= Mpad) return;

  int v = 0;
  #pragma unroll
  for (int i = 1; i < NLEV; ++i) if (rt * TM >= starts[i]) v = i;

  const int tid = threadIdx.x;            // 0..255
  const int lane = tid & 63, wave = tid >> 6;   // 4 waves
  const int wm = (wave >> 1) * 64, wn = (wave & 1) * 64;
  const int fm = lane & 15;
  const int cb = lane >> 4;

  // A staging: 2 threads per row, 2 chunks (16 consecutive floats) each
  const int ar = tid >> 1;       // 0..127
  const int ah0 = (tid & 1) * 2; // chunks ah0, ah0+1
  int prow = perm[rt * TM + ar];
  if (prow < 0) prow = 0;
  const float* xrow = x + (size_t)prow * D + ah0 * 8;
  const int sw = (ar >> 1) & 3;
  const int aslot0 = ar * BK + (((ah0    ) ^ sw) << 3);
  const int aslot1 = ar * BK + (((ah0 + 1) ^ sw) << 3);

  const u16* wb = weff + ((size_t)v * D + ct * TN) * D;
  // B staging: 512 chunks of 16B, 2 per thread, swizzled at source
  const int c0i = tid;
  const int c1i = 256 + tid;
  const int n0 = c0i >> 2, s0 = c0i & 3, kc0 = s0 ^ ((n0 >> 1) & 3);
  const int n1 = c1i >> 2, s1 = c1i & 3, kc1 = s1 ^ ((n1 >> 1) & 3);
  const u16* gb0 = wb + n0 * D + kc0 * 8;
  const u16* gb1 = wb + n1 * D + kc1 * 8;
  const int bdst0 = c0i * 8, bdst1 = c1i * 8;

  f32x4 acc[4][4];
  #pragma unroll
  for (int i = 0; i < 4; ++i)
    #pragma unroll
    for (int j = 0; j < 4; ++j) acc[i][j] = (f32x4){0.f, 0.f, 0.f, 0.f};

  // ---- prologue: stage A(0) direct, x(1)->cf, issue B(0); full drain once --
  {
    const f32x4* xp = (const f32x4*)xrow;
    f32x4 f0 = xp[0], f1 = xp[1], f2 = xp[2], f3 = xp[3];
    u16x8 cA, cB;
    #pragma unroll
    for (int q = 0; q < 4; ++q) {
      cA[q] = f2bf(f0[q]); cA[4 + q] = f2bf(f1[q]);
      cB[q] = f2bf(f2[q]); cB[4 + q] = f2bf(f3[q]);
    }
    *(u16x8*)(As[0] + aslot0) = cA;
    *(u16x8*)(As[0] + aslot1) = cB;
  }
  f32x4 cf0, cf1, cf2, cf3;   // x data for iter i+1
  {
    const f32x4* xp = (const f32x4*)(xrow + BK);
    cf0 = xp[0]; cf1 = xp[1]; cf2 = xp[2]; cf3 = xp[3];
  }
  __builtin_amdgcn_global_load_lds(
      (const __attribute__((address_space(1))) void*)gb0,
      (__attribute__((address_space(3))) void*)(Bs[0] + bdst0), 16, 0, 0);
  __builtin_amdgcn_global_load_lds(
      (const __attribute__((address_space(1))) void*)gb1,
      (__attribute__((address_space(3))) void*)(Bs[0] + bdst1), 16, 0, 0);
  asm volatile("s_waitcnt vmcnt(0)" ::: "memory");
  asm volatile("s_waitcnt lgkmcnt(0)" ::: "memory");
  __builtin_amdgcn_s_barrier();
  __builtin_amdgcn_sched_barrier(0);

  int p = 0;
  for (int i = 0; i < NITER; ++i) {
    const bool hn = (i + 1 < NITER);
    // (1) issue B prefetch for iter i+1 into buffer p^1 -- FIRST in vmem FIFO
    if (hn) {
      const int k1o = (i + 1) * BK;
      __builtin_amdgcn_global_load_lds(
          (const __attribute__((address_space(1))) void*)(gb0 + k1o),
          (__attribute__((address_space(3))) void*)(Bs[p ^ 1] + bdst0), 16, 0, 0);
      __builtin_amdgcn_global_load_lds(
          (const __attribute__((address_space(1))) void*)(gb1 + k1o),
          (__attribute__((address_space(3))) void*)(Bs[p ^ 1] + bdst1), 16, 0, 0);
    }
    asm volatile("" ::: "memory");   // pin FIFO order: B(i+1) before x(i+2)
    // (2) issue x load for iter i+2
    f32x4 nf0, nf1, nf2, nf3;
    if (i + 2 < NITER) {
      const f32x4* xp = (const f32x4*)(xrow + (i + 2) * BK);
      nf0 = xp[0]; nf1 = xp[1]; nf2 = xp[2]; nf3 = xp[3];
    }
    // (3) compute on buffer p
    s16x8 af[4], bf[4];
    #pragma unroll
    for (int t4 = 0; t4 < 4; ++t4) {
      const int m = wm + t4 * 16 + fm;
      af[t4] = *(const s16x8*)(As[p] + m * BK + ((cb ^ ((m >> 1) & 3)) << 3));
      const int n = wn + t4 * 16 + fm;
      bf[t4] = *(const s16x8*)(Bs[p] + n * BK + ((cb ^ ((n >> 1) & 3)) << 3));
    }
    __builtin_amdgcn_s_setprio(1);
    #pragma unroll
    for (int tm = 0; tm < 4; ++tm)
      #pragma unroll
      for (int tn = 0; tn < 4; ++tn)
        acc[tm][tn] = __builtin_amdgcn_mfma_f32_16x16x32_bf16(af[tm], bf[tn], acc[tm][tn], 0, 0, 0);
    __builtin_amdgcn_s_setprio(0);
    if (hn) {
      // (4) f2bf + ds_write A(i+1) (x data loaded one iter ago)
      u16x8 cA, cB;
      #pragma unroll
      for (int q = 0; q < 4; ++q) {
        cA[q] = f2bf(cf0[q]); cA[4 + q] = f2bf(cf1[q]);
        cB[q] = f2bf(cf2[q]); cB[4 + q] = f2bf(cf3[q]);
      }
      *(u16x8*)(As[p ^ 1] + aslot0) = cA;
      *(u16x8*)(As[p ^ 1] + aslot1) = cB;
      if (i + 2 < NITER) { cf0 = nf0; cf1 = nf1; cf2 = nf2; cf3 = nf3; }
      // (5) counted pre-barrier wait: FIFO here = [B(i+1)x2, x(i+2)x4] with
      // x(i+1) already drained by its f2bf use above. vmcnt(4) drains exactly
      // B(i+1) and keeps all four x(i+2) loads in flight across the barrier.
      if (i + 2 < NITER) asm volatile("s_waitcnt vmcnt(4)" ::: "memory");
      else               asm volatile("s_waitcnt vmcnt(0)" ::: "memory");
      asm volatile("s_waitcnt lgkmcnt(0)" ::: "memory");
      __builtin_amdgcn_s_barrier();
      __builtin_amdgcn_sched_barrier(0);
    }
    p ^= 1;
  }

  // Epilogue: C frag col=lane&15, row=(lane>>4)*4+reg; scatter rows via perm
  float bv[4];
  #pragma unroll
  for (int tn = 0; tn < 4; ++tn) bv[tn] = bias[ct * TN + wn + tn * 16 + fm];
  #pragma unroll
  for (int tm = 0; tm < 4; ++tm) {
    #pragma unroll
    for (int r = 0; r < 4; ++r) {
      const int mrow = wm + tm * 16 + (lane >> 4) * 4 + r;
      const int p2 = perm[rt * TM + mrow];
      if (p2 >= 0) {
        float* o = out + (size_t)p2 * D + ct * TN + wn + fm;
        #pragma unroll
        for (int tn = 0; tn < 4; ++tn)
          o[tn * 16] = acc[tm][tn][r] + bv[tn];
      }
    }
  }
}

extern "C" void kernel_launch(void* const* d_in, const int* in_sizes, int n_in,
                              void* d_out, int out_size, void* d_ws, size_t ws_size,
                              hipStream_t stream) {
  const float* x    = (const float*)d_in[0];
  const int*   val  = (const int*)d_in[1];
  const float* W    = (const float*)d_in[2];
  const float* lg   = (const float*)d_in[3];
  const float* attn = (const float*)d_in[4];
  const float* bias = (const float*)d_in[5];
  float* out = (float*)d_out;

  char* ws = (char*)d_ws;
  int* starts = (int*)(ws + 0);          // 11 ints
  u16* hist   = (u16*)(ws + 64);         // 128*10 u16
  int* perm   = (int*)(ws + 2688);       // 34048 ints -> ends 138880
  u16* weff   = (u16*)(ws + 139264);     // 10*512*512 bf16 = 5.24 MB

  k1<<<DD / 256 + NHB, 256, 0, stream>>>(W, lg, attn, val, weff, hist, perm);
  k2<<<NHB, 256, 0, stream>>>(val, hist, perm, starts);
  k3<<<NBLK, 256, 0, stream>>>(x, weff, perm, starts, bias, out);
}

// Round 9
// 174.950 us; speedup vs baseline: 1.4879x; 1.4879x over previous
//
#include <hip/hip_runtime.h>

#define B_N 32768
#define D 512
#define DD (D * D)
#define NLEV 10
#define TM 128
#define TN 256
#define BK 32
#define NITER (D / BK)            // 16
#define NHB 128                   // histogram blocks (B_N / 256)
#define CONVB 2048                // x->bf16 conversion blocks (B_N*D/8192)
#define MROWS_MAX 34048           // 32768 + 10*128 padding headroom
#define MAX_RT (MROWS_MAX / TM)   // 266

typedef unsigned short u16;
typedef short s16x8 __attribute__((ext_vector_type(8)));
typedef u16 u16x8 __attribute__((ext_vector_type(8)));
typedef float f32x4 __attribute__((ext_vector_type(4)));

__device__ __forceinline__ u16 f2bf(float f) {
  union { float f; unsigned u; } v; v.f = f;
  unsigned r = v.u + 0x7fffu + ((v.u >> 16) & 1u);  // RNE
  return (u16)(r >> 16);
}
__device__ __forceinline__ int clampv(int v) {
  return v < 0 ? 0 : (v > NLEV - 1 ? NLEV - 1 : v);
}

// ---- K1: weff-build (0..1023) UNION hist+perm-fill (1024..1151)
// UNION x->bf16 conversion (1152..3199) -------------------------------------
__global__ void k1(const float* __restrict__ W, const float* __restrict__ lg,
                   const float* __restrict__ attn, const int* __restrict__ val,
                   const float* __restrict__ x,
                   u16* __restrict__ weff, u16* __restrict__ hist,
                   int* __restrict__ perm, u16* __restrict__ xa) {
  const int t = threadIdx.x;
  if (blockIdx.x < DD / 256) {
    __shared__ float c[NLEV * NLEV];
    if (t < NLEV) {
      float g[NLEV], a[NLEV], mx = -1e30f;
      #pragma unroll
      for (int l = 0; l < NLEV; ++l) {
        g[l] = 1.0f / (1.0f + expf(-lg[l]));
        a[l] = attn[t * NLEV + l];
        mx = fmaxf(mx, a[l]);
      }
      float s = 0.f;
      #pragma unroll
      for (int l = 0; l < NLEV; ++l) { a[l] = expf(a[l] - mx); s += a[l]; }
      float inv = 1.0f / s;
      #pragma unroll
      for (int l = 0; l < NLEV; ++l) {
        float cc = 0.3f * a[l] * inv * g[l];
        if (l == t) cc += 0.7f * g[t];
        c[t * NLEV + l] = cc;
      }
    }
    __syncthreads();
    const int idx = blockIdx.x * 256 + t;
    float w[NLEV];
    #pragma unroll
    for (int l = 0; l < NLEV; ++l) w[l] = W[l * DD + idx];
    #pragma unroll
    for (int v = 0; v < NLEV; ++v) {
      float s = 0.f;
      #pragma unroll
      for (int l = 0; l < NLEV; ++l) s += c[v * NLEV + l] * w[l];
      weff[v * DD + idx] = f2bf(s);
    }
  } else if (blockIdx.x < DD / 256 + NHB) {
    __shared__ int lc[NLEV];
    const int b = blockIdx.x - DD / 256;   // 0..127
    if (t < NLEV) lc[t] = 0;
    __syncthreads();
    const int gid = b * 256 + t;
    atomicAdd(&lc[clampv(val[gid])], 1);
    perm[gid] = -1;
    if (b < (MROWS_MAX - B_N) / 256) perm[B_N + b * 256 + t] = -1;
    __syncthreads();
    if (t < NLEV) hist[b * NLEV + t] = (u16)lc[t];
  } else {
    // x -> bf16, original row order; 32 elems/thread, fully coalesced
    const int b2 = blockIdx.x - (DD / 256 + NHB);       // 0..2047
    const size_t base = (size_t)b2 * 8192 + t * 32;
    const f32x4* xs = (const f32x4*)(x + base);
    u16x8* xd = (u16x8*)(xa + base);
    #pragma unroll
    for (int q = 0; q < 4; ++q) {
      f32x4 a = xs[2 * q], bqq = xs[2 * q + 1];
      u16x8 cc;
      #pragma unroll
      for (int r = 0; r < 4; ++r) { cc[r] = f2bf(a[r]); cc[4 + r] = f2bf(bqq[r]); }
      xd[q] = cc;
    }
  }
}

// ---- K2: deterministic counting-sort scatter (prefix over hist table) ------
__global__ void k2(const int* __restrict__ val, const u16* __restrict__ hist,
                   int* __restrict__ perm, int* __restrict__ starts) {
  __shared__ int h[NHB * NLEV];
  __shared__ int st[NLEV + 1];
  __shared__ int cnt[NLEV];
  __shared__ int lc[NLEV];
  const int t = threadIdx.x, b = blockIdx.x;
  for (int i = t; i < NHB * NLEV; i += 256) h[i] = hist[i];
  if (t < NLEV) lc[t] = 0;
  __syncthreads();
  if (t < NLEV) {
    int run = 0;
    for (int bb = 0; bb < NHB; ++bb) {
      int x = h[bb * NLEV + t];
      h[bb * NLEV + t] = run;
      run += x;
    }
    cnt[t] = run;
  }
  __syncthreads();
  if (t == 0) {
    int s = 0;
    for (int v = 0; v < NLEV; ++v) {
      st[v] = s;
      s += (cnt[v] + TM - 1) & ~(TM - 1);
    }
    st[NLEV] = s;
  }
  __syncthreads();
  const int gid = b * 256 + t;
  const int v = clampv(val[gid]);
  const int pos = atomicAdd(&lc[v], 1);
  perm[st[v] + h[b * NLEV + v] + pos] = gid;
  if (b == 0 && t <= NLEV) starts[t] = st[t];
}

// ---- K3: grouped GEMM, 128x256, ALL-gload_lds triple-buffer, depth-2 -------
// Key change vs the 65us R4 kernel: A comes from pre-converted bf16 xa via
// global_load_lds with per-lane gathered, pre-swizzled sources -> the K-loop
// has ZERO register-consumed vmem loads, so no implicit vmcnt waits. R4's
// f2bf(x) register consume forced a 1-body-slack drain of the whole vmem
// FIFO every iteration (why counted vmcnt gained only 4%). Now A and B are
// both prefetched 2 iterations ahead; the only waits are explicit vmcnt(3).
__global__ __launch_bounds__(512, 4) void k3(
    const u16* __restrict__ xa, const u16* __restrict__ weff,
    const int* __restrict__ perm, const int* __restrict__ starts,
    const float* __restrict__ bias, float* __restrict__ out) {
  __shared__ u16 As[3][TM * BK];   // 3 x 8 KB
  __shared__ u16 Bs[3][TN * BK];   // 3 x 16 KB -> 72 KB, 2 blocks/CU

  const int ct = blockIdx.x, rt = blockIdx.y;
  const int Mpad = starts[NLEV];
  if (rt * TM >= Mpad) return;

  int v = 0;
  #pragma unroll
  for (int i = 1; i < NLEV; ++i) if (rt * TM >= starts[i]) v = i;

  const int tid = threadIdx.x;
  const int lane = tid & 63, wave = tid >> 6;
  const int wm = (wave >> 2) * 64, wn = (wave & 3) * 64;
  const int fm = lane & 15;
  const int cb = lane >> 4;

  // A staging via gload_lds: chunk c = tid -> (row ar=c>>2, slot s=c&3);
  // slot s must hold k-chunk (s ^ sw(ar)) so the R4-verified XOR read works.
  const int ar = tid >> 2;
  const int aslt = tid & 3;
  int prow = perm[rt * TM + ar];
  if (prow < 0) prow = 0;
  const u16* ga = xa + (size_t)prow * D + ((aslt ^ ((ar >> 1) & 3)) << 3);
  const int adst = tid * 8;      // u16 elements (16B per chunk, linear)

  const u16* wb = weff + ((size_t)v * D + ct * TN) * D;
  // B staging (unchanged, verified): 2 chunks/thread, source pre-swizzled
  const int c0i = wave * 64 + lane;
  const int c1i = 512 + c0i;
  const int n0 = c0i >> 2, s0 = c0i & 3, kc0 = s0 ^ ((n0 >> 1) & 3);
  const int n1 = c1i >> 2, s1 = c1i & 3, kc1 = s1 ^ ((n1 >> 1) & 3);
  const u16* gb0 = wb + n0 * D + kc0 * 8;
  const u16* gb1 = wb + n1 * D + kc1 * 8;
  const int bdst0 = c0i * 8, bdst1 = c1i * 8;

  f32x4 acc[4][4];
  #pragma unroll
  for (int i = 0; i < 4; ++i)
    #pragma unroll
    for (int j = 0; j < 4; ++j) acc[i][j] = (f32x4){0.f, 0.f, 0.f, 0.f};

  // ---- prologue: stage steps 0 and 1; one-time full drain ----
  __builtin_amdgcn_global_load_lds(
      (const __attribute__((address_space(1))) void*)ga,
      (__attribute__((address_space(3))) void*)(As[0] + adst), 16, 0, 0);
  __builtin_amdgcn_global_load_lds(
      (const __attribute__((address_space(1))) void*)gb0,
      (__attribute__((address_space(3))) void*)(Bs[0] + bdst0), 16, 0, 0);
  __builtin_amdgcn_global_load_lds(
      (const __attribute__((address_space(1))) void*)gb1,
      (__attribute__((address_space(3))) void*)(Bs[0] + bdst1), 16, 0, 0);
  __builtin_amdgcn_global_load_lds(
      (const __attribute__((address_space(1))) void*)(ga + BK),
      (__attribute__((address_space(3))) void*)(As[1] + adst), 16, 0, 0);
  __builtin_amdgcn_global_load_lds(
      (const __attribute__((address_space(1))) void*)(gb0 + BK),
      (__attribute__((address_space(3))) void*)(Bs[1] + bdst0), 16, 0, 0);
  __builtin_amdgcn_global_load_lds(
      (const __attribute__((address_space(1))) void*)(gb1 + BK),
      (__attribute__((address_space(3))) void*)(Bs[1] + bdst1), 16, 0, 0);
  asm volatile("s_waitcnt vmcnt(0)" ::: "memory");
  __builtin_amdgcn_s_barrier();
  __builtin_amdgcn_sched_barrier(0);

  // rotating buffers: R = read (step i), M = in-flight (i+1), W = target (i+2)
  u16 *Arr = (u16*)As[0], *Am = (u16*)As[1], *Aw = (u16*)As[2];
  u16 *Brr = (u16*)Bs[0], *Bm = (u16*)Bs[1], *Bw = (u16*)Bs[2];

  for (int i = 0; i < NITER; ++i) {
    const bool h2 = (i + 2 < NITER);
    // (1) issue step-(i+2) staging (3 gload_lds, depth-2 prefetch)
    if (h2) {
      const int ko = (i + 2) * BK;
      __builtin_amdgcn_global_load_lds(
          (const __attribute__((address_space(1))) void*)(ga + ko),
          (__attribute__((address_space(3))) void*)(Aw + adst), 16, 0, 0);
      __builtin_amdgcn_global_load_lds(
          (const __attribute__((address_space(1))) void*)(gb0 + ko),
          (__attribute__((address_space(3))) void*)(Bw + bdst0), 16, 0, 0);
      __builtin_amdgcn_global_load_lds(
          (const __attribute__((address_space(1))) void*)(gb1 + ko),
          (__attribute__((address_space(3))) void*)(Bw + bdst1), 16, 0, 0);
    }
    // (2) compute on R buffers (step i landed: counted wait + barrier earlier)
    s16x8 af[4], bf[4];
    #pragma unroll
    for (int t4 = 0; t4 < 4; ++t4) {
      const int m = wm + t4 * 16 + fm;
      af[t4] = *(const s16x8*)(Arr + m * BK + ((cb ^ ((m >> 1) & 3)) << 3));
      const int n = wn + t4 * 16 + fm;
      bf[t4] = *(const s16x8*)(Brr + n * BK + ((cb ^ ((n >> 1) & 3)) << 3));
    }
    __builtin_amdgcn_s_setprio(1);
    #pragma unroll
    for (int tm = 0; tm < 4; ++tm)
      #pragma unroll
      for (int tn = 0; tn < 4; ++tn)
        acc[tm][tn] = __builtin_amdgcn_mfma_f32_16x16x32_bf16(af[tm], bf[tn], acc[tm][tn], 0, 0, 0);
    __builtin_amdgcn_s_setprio(0);
    if (i + 1 < NITER) {
      // (3) counted pre-barrier wait. FIFO: [(i+1)x3 older, (i+2)x3 newer];
      // vmcnt(3) drains exactly the (i+1) group, keeps (i+2) in flight.
      if (h2) asm volatile("s_waitcnt vmcnt(3)" ::: "memory");
      else    asm volatile("s_waitcnt vmcnt(0)" ::: "memory");
      asm volatile("s_waitcnt lgkmcnt(0)" ::: "memory");  // frag reads done
      __builtin_amdgcn_s_barrier();
      __builtin_amdgcn_sched_barrier(0);
      // rotate: R <- M, M <- W, W <- old R
      u16* t;
      t = Arr; Arr = Am; Am = Aw; Aw = t;
      t = Brr; Brr = Bm; Bm = Bw; Bw = t;
    }
  }

  // Epilogue: C frag col=lane&15, row=(lane>>4)*4+reg; scatter rows via perm
  float bv[4];
  #pragma unroll
  for (int tn = 0; tn < 4; ++tn) bv[tn] = bias[ct * TN + wn + tn * 16 + fm];
  #pragma unroll
  for (int tm = 0; tm < 4; ++tm) {
    #pragma unroll
    for (int r = 0; r < 4; ++r) {
      const int mrow = wm + tm * 16 + (lane >> 4) * 4 + r;
      const int p2 = perm[rt * TM + mrow];
      if (p2 >= 0) {
        float* o = out + (size_t)p2 * D + ct * TN + wn + fm;
        #pragma unroll
        for (int tn = 0; tn < 4; ++tn)
          o[tn * 16] = acc[tm][tn][r] + bv[tn];
      }
    }
  }
}

extern "C" void kernel_launch(void* const* d_in, const int* in_sizes, int n_in,
                              void* d_out, int out_size, void* d_ws, size_t ws_size,
                              hipStream_t stream) {
  const float* x    = (const float*)d_in[0];
  const int*   val  = (const int*)d_in[1];
  const float* W    = (const float*)d_in[2];
  const float* lg   = (const float*)d_in[3];
  const float* attn = (const float*)d_in[4];
  const float* bias = (const float*)d_in[5];
  float* out = (float*)d_out;

  char* ws = (char*)d_ws;
  int* starts = (int*)(ws + 0);          // 11 ints
  u16* hist   = (u16*)(ws + 64);         // 128*10 u16
  int* perm   = (int*)(ws + 2688);       // 34048 ints -> ends 138880
  u16* weff   = (u16*)(ws + 139264);     // 10*512*512 bf16 -> ends 5382144
  u16* xa     = (u16*)(ws + 5382144);    // 32768*512 bf16 = 33.6MB -> 38.9MB

  k1<<<DD / 256 + NHB + CONVB, 256, 0, stream>>>(W, lg, attn, val, x,
                                                 weff, hist, perm, xa);
  k2<<<NHB, 256, 0, stream>>>(val, hist, perm, starts);
  k3<<<dim3(D / TN, MAX_RT), 512, 0, stream>>>(xa, weff, perm, starts, bias, out);
}